// Round 4
// baseline (64.104 us; speedup 1.0000x reference)
//
#include <hip/hip_runtime.h>

// 5-level wavedec (filter len 8, pywt 'symmetric'), 4096 rows of 8192 f32.
// Lengths: 8192 -> 4099 -> 2053 -> 1030 -> 518 -> 262
// Out: approx(262) @0, d5(262), d4(518), d3(1030), d2(2053), d1(4099).
// LDS approx buffers use pad-1-per-8 layout: phys(i) = i + (i>>3) (stride 9,
// gcd(9,32)=1 -> lane bases spread across all banks, ~2-way = free).
// Window offsets from base are compile-time constants -> ds_read2_b32 fusion.

static constexpr int ROWS = 4096;
static constexpr int N0 = 8192;
static constexpr int L1n = 4099, L2n = 2053, L3n = 1030, L4n = 518, L5n = 262;
static constexpr size_t OFF_D5 = 1073152u;
static constexpr size_t OFF_D4 = 2146304u;
static constexpr size_t OFF_D3 = 4268032u;
static constexpr size_t OFF_D2 = 8486912u;
static constexpr size_t OFF_D1 = 16896000u;

__device__ __forceinline__ int physidx(int i) { return i + (i >> 3); }

template <bool SRCPAD, bool DSTPAD>
__device__ __forceinline__ void dwt_level(
    const float* __restrict__ src, int n, int m,
    const float* __restrict__ h, const float* __restrict__ g,
    float* __restrict__ adst, float* __restrict__ ddst, int tid)
{
    const int ngroups = (m + 3) >> 2;
    const int jin_max = (n - 10) >> 3;   // interior iff 1 <= j <= jin_max
    for (int j = tid; j < ngroups; j += 256) {
        const int p0 = 4 * j;
        if (j >= 1 && j <= jin_max && p0 + 3 < m) {
            float w[16];
            if (SRCPAD) {
                // logical window [8j-6, 8j+9]; phys base 9j-7, fixed rel offs
                const float* __restrict__ p = src + (9 * j - 7);
                w[0] = p[0];  w[1] = p[1];  w[2] = p[2];  w[3] = p[3];
                w[4] = p[4];  w[5] = p[5];
                w[6] = p[7];  w[7] = p[8];  w[8] = p[9];  w[9] = p[10];
                w[10] = p[11]; w[11] = p[12]; w[12] = p[13]; w[13] = p[14];
                w[14] = p[16]; w[15] = p[17];
            } else {
                const float2* __restrict__ s2 =
                    reinterpret_cast<const float2*>(src + (8 * j - 6));
#pragma unroll
                for (int t = 0; t < 8; ++t) {
                    const float2 v = s2[t];
                    w[2 * t] = v.x; w[2 * t + 1] = v.y;
                }
            }
            float aa[4], dd[4];
#pragma unroll
            for (int r = 0; r < 4; ++r) {
                float a = 0.f, d = 0.f;
#pragma unroll
                for (int q = 0; q < 8; ++q) {
                    const float v = w[2 * r + 7 - q];   // src[2(p0+r)+1-q]
                    a = fmaf(h[q], v, a);
                    d = fmaf(g[q], v, d);
                }
                aa[r] = a; dd[r] = d;
            }
            if (DSTPAD) {
                float* __restrict__ q4 = adst + (4 * j + (j >> 1));
#pragma unroll
                for (int r = 0; r < 4; ++r) q4[r] = aa[r];
            } else {
#pragma unroll
                for (int r = 0; r < 4; ++r) adst[p0 + r] = aa[r];
            }
#pragma unroll
            for (int r = 0; r < 4; ++r) ddst[p0 + r] = dd[r];
        } else {
            // edge groups: branchy symmetric-reflect path (few per level)
#pragma unroll 4
            for (int r = 0; r < 4; ++r) {
                const int pos = p0 + r;
                if (pos >= m) break;
                const int s0 = 2 * pos + 1;
                float a = 0.f, d = 0.f;
#pragma unroll
                for (int q = 0; q < 8; ++q) {
                    int s = s0 - q;
                    int idx = (s < 0) ? (-1 - s) : ((s >= n) ? (2 * n - 1 - s) : s);
                    const float v = SRCPAD ? src[physidx(idx)] : src[idx];
                    a = fmaf(h[q], v, a);
                    d = fmaf(g[q], v, d);
                }
                ddst[pos] = d;
                if (DSTPAD) adst[physidx(pos)] = a;
                else        adst[pos] = a;
            }
        }
    }
}

__global__ __launch_bounds__(256, 5)
void wavedec5_kernel(const float* __restrict__ x,
                     const float* __restrict__ dlo,
                     const float* __restrict__ dhi,
                     float* __restrict__ out)
{
    __shared__ __align__(16) float bufA[4612];  // padded 4099 -> 4611
    __shared__ __align__(16) float bufB[2312];  // padded 2053 -> 2309

    const int row = blockIdx.x;
    const int tid = threadIdx.x;

    float h[8], g[8];
#pragma unroll
    for (int i = 0; i < 8; ++i) { h[i] = dlo[i]; g[i] = dhi[i]; }

    const float* __restrict__ xr = x + (size_t)row * N0;

    // L1: global -> bufA (padded), d1 -> global
    dwt_level<false, true>(xr, N0, L1n, h, g, bufA,
                           out + OFF_D1 + (size_t)row * L1n, tid);
    __syncthreads();
    // L2: bufA -> bufB, d2 -> global
    dwt_level<true, true>(bufA, L1n, L2n, h, g, bufB,
                          out + OFF_D2 + (size_t)row * L2n, tid);
    __syncthreads();
    // L3: bufB -> bufA (a1 dead), d3 -> global
    dwt_level<true, true>(bufB, L2n, L3n, h, g, bufA,
                          out + OFF_D3 + (size_t)row * L3n, tid);
    __syncthreads();
    // L4: bufA -> bufB (a2 dead), d4 -> global
    dwt_level<true, true>(bufA, L3n, L4n, h, g, bufB,
                          out + OFF_D4 + (size_t)row * L4n, tid);
    __syncthreads();
    // L5: bufB -> approx & d5 straight to global
    dwt_level<true, false>(bufB, L4n, L5n, h, g,
                           out + (size_t)row * L5n,
                           out + OFF_D5 + (size_t)row * L5n, tid);
}

extern "C" void kernel_launch(void* const* d_in, const int* in_sizes, int n_in,
                              void* d_out, int out_size, void* d_ws, size_t ws_size,
                              hipStream_t stream) {
    const float* x   = (const float*)d_in[0];
    const float* dlo = (const float*)d_in[1];
    const float* dhi = (const float*)d_in[2];
    float* out = (float*)d_out;
    wavedec5_kernel<<<ROWS, 256, 0, stream>>>(x, dlo, dhi, out);
}